// Round 2
// baseline (213.193 us; speedup 1.0000x reference)
//
#include <hip/hip_runtime.h>
#include <hip/hip_bf16.h>

// Shapes (fixed by the reference):
// lfi:    [B, U, H, W, C] f32   B=4, U=81, H=64, W=64, C=4
// f_maps: [B, H, W, F]    f32   F=32
// out:    [B, U, H, W, F] f32
#define BB 4
#define UU 81
#define HH 64
#define WW 64
#define CC 4
#define FF 32

// ---------------------------------------------------------------------------
// Kernel A: mask[b][y][f] = mean_h(f_maps[b,h,y,f]) / max_y(mean_h(...))
// One block per b, 1024 threads; each thread owns 2 of the W*F=2048 (w,f)
// slots. h-loop loads are fully coalesced (consecutive threads hit
// consecutive addresses). Max over w via LDS tree.
// ---------------------------------------------------------------------------
__global__ __launch_bounds__(1024) void mask_kernel(
    const float* __restrict__ fmaps, float* __restrict__ mask) {
    const int b = blockIdx.x;
    const int t = threadIdx.x;                 // 0..1023
    __shared__ float hv[WW * FF];              // 2048 floats = 8 KB
    const float* fb = fmaps + (size_t)b * HH * WW * FF;

    float v[2];
#pragma unroll
    for (int r = 0; r < 2; ++r) {
        const int idx = t + r * 1024;          // idx = w*F + f
        float s = 0.f;
#pragma unroll 4
        for (int h = 0; h < HH; ++h) s += fb[h * WW * FF + idx];
        v[r] = s * (1.f / HH);
        hv[idx] = v[r];
    }
    __syncthreads();

    // tree max over w (rows of hv[w][f]); writers rows [0,s), readers [s,2s)
    for (int s = WW / 2; s > 0; s >>= 1) {
#pragma unroll
        for (int r = 0; r < 2; ++r) {
            const int idx = t + r * 1024;
            const int w = idx / FF, f = idx % FF;
            if (w < s) hv[idx] = fmaxf(hv[idx], hv[(w + s) * FF + f]);
        }
        __syncthreads();
    }

#pragma unroll
    for (int r = 0; r < 2; ++r) {
        const int idx = t + r * 1024;
        const int f = idx & (FF - 1);
        mask[(size_t)b * WW * FF + idx] = v[r] / hv[f];  // hv[0*F+f] = max_w
    }
}

// ---------------------------------------------------------------------------
// Kernel B: out[b,u,y,x,f] = mean_c(lfi[b,u,y,x,:]) * mask[b,y,f]
// One thread per output float4 (f-group). Consecutive threads -> consecutive
// 16B stores (fully coalesced 1KB/wave). lfi row [b,u,y,x,:] is exactly one
// float4 (C=4); 8 neighboring lanes share it via L1.
// ---------------------------------------------------------------------------
__global__ __launch_bounds__(256) void out_kernel(
    const float4* __restrict__ lfi4,   // [B*U*H*W] float4 (C=4 contiguous)
    const float4* __restrict__ mask4,  // [B*W*F/4] float4
    float4* __restrict__ out4) {       // [B*U*H*W*F/4]
    const size_t idx = (size_t)blockIdx.x * blockDim.x + threadIdx.x;
    // idx = (((b*U + u)*H + y)*W + x)*(F/4) + f4
    const int f4 = (int)(idx & 7);           // F/4 = 8
    const size_t rest = idx >> 3;            // ((b*U+u)*H + y)*W + x  == lfi4 index
    const size_t rest2 = rest >> 6;          // (b*U+u)*H + y
    const int y = (int)(rest2 & 63);
    const int bu = (int)(rest2 >> 6);        // b*U + u
    const int b = bu / UU;                   // small int div -> magic mul

    const float4 lf = lfi4[rest];
    const float m = (lf.x + lf.y + lf.z + lf.w) * 0.25f;
    const float4 mk = mask4[((size_t)b * WW + y) * (FF / 4) + f4];

    float4 o;
    o.x = m * mk.x;
    o.y = m * mk.y;
    o.z = m * mk.z;
    o.w = m * mk.w;
    out4[idx] = o;
}

extern "C" void kernel_launch(void* const* d_in, const int* in_sizes, int n_in,
                              void* d_out, int out_size, void* d_ws, size_t ws_size,
                              hipStream_t stream) {
    const float* lfi = (const float*)d_in[0];
    const float* fmaps = (const float*)d_in[1];
    float* out = (float*)d_out;
    float* mask = (float*)d_ws;  // B*W*F = 8192 floats = 32 KB

    mask_kernel<<<BB, 1024, 0, stream>>>(fmaps, mask);

    const size_t total4 = (size_t)BB * UU * HH * WW * (FF / 4);  // 10,616,832
    const int block = 256;
    const int grid = (int)((total4 + block - 1) / block);        // 41,472
    out_kernel<<<grid, block, 0, stream>>>(
        (const float4*)lfi, (const float4*)mask, (float4*)out);
}

// Round 8
// 209.649 us; speedup vs baseline: 1.0169x; 1.0169x over previous
//
#include <hip/hip_runtime.h>
#include <hip/hip_bf16.h>

// Shapes (fixed by the reference):
// lfi:    [B, U, H, W, C] f32   B=4, U=81, H=64, W=64, C=4
// f_maps: [B, H, W, F]    f32   F=32
// out:    [B, U, H, W, F] f32
#define BB 4
#define UU 81
#define HH 64
#define WW 64
#define CC 4
#define FF 32

// Native Clang vector type: layout-compatible with float4, accepted by
// __builtin_nontemporal_store (HIP_vector_type is a class and is NOT).
typedef float fx4 __attribute__((ext_vector_type(4)));

// ---------------------------------------------------------------------------
// Kernel A: mask[b][y][f] = mean_h(f_maps[b,h,y,f]) / max_y(mean_h(...))
// One block per b, 1024 threads; each thread owns 2 of the W*F=2048 (w,f)
// slots. h-loop loads are fully coalesced. Max over w via LDS tree.
// ---------------------------------------------------------------------------
__global__ __launch_bounds__(1024) void mask_kernel(
    const float* __restrict__ fmaps, float* __restrict__ mask) {
    const int b = blockIdx.x;
    const int t = threadIdx.x;                 // 0..1023
    __shared__ float hv[WW * FF];              // 2048 floats = 8 KB
    const float* fb = fmaps + (size_t)b * HH * WW * FF;

    float v[2];
#pragma unroll
    for (int r = 0; r < 2; ++r) {
        const int idx = t + r * 1024;          // idx = w*F + f
        float s = 0.f;
#pragma unroll 4
        for (int h = 0; h < HH; ++h) s += fb[h * WW * FF + idx];
        v[r] = s * (1.f / HH);
        hv[idx] = v[r];
    }
    __syncthreads();

    // tree max over w (rows of hv[w][f])
    for (int s = WW / 2; s > 0; s >>= 1) {
#pragma unroll
        for (int r = 0; r < 2; ++r) {
            const int idx = t + r * 1024;
            const int w = idx / FF, f = idx % FF;
            if (w < s) hv[idx] = fmaxf(hv[idx], hv[(w + s) * FF + f]);
        }
        __syncthreads();
    }

#pragma unroll
    for (int r = 0; r < 2; ++r) {
        const int idx = t + r * 1024;
        const int f = idx & (FF - 1);
        mask[(size_t)b * WW * FF + idx] = v[r] / hv[f];  // hv[0*F+f] = max_w
    }
}

// ---------------------------------------------------------------------------
// Kernel B: out[b,u,y,x,f] = mean_c(lfi[b,u,y,x,:]) * mask[b,y,f]
// grid = (chunks, B): blockIdx.y = b (no int div). Each thread produces
// NPT=8 fx4 outputs at blockDim-stride offsets: every iteration's wave
// stores 1KB fully-coalesced, and 8 independent lfi loads are in flight
// per thread (MLP to hide HBM latency). Nontemporal stores: output is
// pure streaming, never re-read.
// ---------------------------------------------------------------------------
#define NPT 8
__global__ __launch_bounds__(256) void out_kernel(
    const fx4* __restrict__ lfi4,   // [B*U*H*W] fx4 (C=4 contiguous)
    const fx4* __restrict__ mask4,  // [B*W*F/4] fx4
    fx4* __restrict__ out4) {       // [B*U*H*W*F/4]
    const int b = blockIdx.y;
    const fx4* __restrict__ lfiB  = lfi4  + (size_t)b * UU * HH * WW;
    const fx4* __restrict__ maskB = mask4 + (size_t)b * WW * (FF / 4);
    fx4* __restrict__ outB        = out4  + (size_t)b * UU * HH * WW * (FF / 4);

    const size_t base = (size_t)blockIdx.x * (256 * NPT) + threadIdx.x;

    fx4 lf[NPT];
    fx4 mk[NPT];
#pragma unroll
    for (int k = 0; k < NPT; ++k) {
        const size_t idx = base + (size_t)k * 256;
        const int f4 = (int)(idx & 7);           // F/4 = 8
        const size_t rest = idx >> 3;            // (u*H + y)*W + x
        const int y = (int)((rest >> 6) & 63);
        lf[k] = lfiB[rest];
        mk[k] = maskB[y * 8 + f4];
    }
#pragma unroll
    for (int k = 0; k < NPT; ++k) {
        const size_t idx = base + (size_t)k * 256;
        const float m = (lf[k].x + lf[k].y + lf[k].z + lf[k].w) * 0.25f;
        fx4 o = m * mk[k];
        __builtin_nontemporal_store(o, &outB[idx]);
    }
}

extern "C" void kernel_launch(void* const* d_in, const int* in_sizes, int n_in,
                              void* d_out, int out_size, void* d_ws, size_t ws_size,
                              hipStream_t stream) {
    const float* lfi = (const float*)d_in[0];
    const float* fmaps = (const float*)d_in[1];
    float* out = (float*)d_out;
    float* mask = (float*)d_ws;  // B*W*F = 8192 floats = 32 KB

    mask_kernel<<<BB, 1024, 0, stream>>>(fmaps, mask);

    const size_t perB4 = (size_t)UU * HH * WW * (FF / 4);  // 2,654,208
    const int grid_x = (int)(perB4 / (256 * NPT));         // 1296 (exact)
    dim3 grid(grid_x, BB);
    out_kernel<<<grid, 256, 0, stream>>>(
        (const fx4*)lfi, (const fx4*)mask, (fx4*)out);
}

// Round 9
// 200.466 us; speedup vs baseline: 1.0635x; 1.0458x over previous
//
#include <hip/hip_runtime.h>
#include <hip/hip_bf16.h>

// Shapes (fixed by the reference):
// lfi:    [B, U, H, W, C] f32   B=4, U=81, H=64, W=64, C=4
// f_maps: [B, H, W, F]    f32   F=32
// out:    [B, U, H, W, F] f32
#define BB 4
#define UU 81
#define HH 64
#define WW 64
#define CC 4
#define FF 32

// Native Clang vector type: valid operand for __builtin_nontemporal_store
// (HIP_vector_type float4 is a class and is rejected).
typedef float fx4 __attribute__((ext_vector_type(4)));

// ws layout (floats): [0, 32768)   = partial[b][hs][slot]  (4*4*2048)
//                     [32768, 40960) = mask[b][y][f]        (4*2048)
#define WS_PARTIAL 0
#define WS_MASK 32768

// ---------------------------------------------------------------------------
// Kernel A1: partial h-sums. grid = (4 h-slices, 4 b), 1024 threads.
// Each block sums 16 h-rows for all 2048 (w,f) slots of its b.
// 16 blocks (vs 4 before) -> 4x the CUs pulling f_maps, fully unrolled
// 16-deep load chain per thread.
// ---------------------------------------------------------------------------
__global__ __launch_bounds__(1024) void mask_partial_kernel(
    const float* __restrict__ fmaps, float* __restrict__ ws) {
    const int hs = blockIdx.x;                 // 0..3
    const int b = blockIdx.y;
    const int t = threadIdx.x;                 // 0..1023
    const float* fb = fmaps + (size_t)b * HH * WW * FF + (size_t)hs * 16 * WW * FF;
    float* part = ws + WS_PARTIAL + ((size_t)b * 4 + hs) * (WW * FF);

#pragma unroll
    for (int r = 0; r < 2; ++r) {
        const int idx = t + r * 1024;          // slot = w*F + f
        float s = 0.f;
#pragma unroll
        for (int h = 0; h < 16; ++h) s += fb[h * WW * FF + idx];
        part[idx] = s;
    }
}

// ---------------------------------------------------------------------------
// Kernel A2: hv = sum of 4 partials (L2-hot), tree-max over w per (b,f),
// write normalized mask. grid = 4 (b), 256 threads, 8 slots/thread.
// ---------------------------------------------------------------------------
__global__ __launch_bounds__(256) void mask_norm_kernel(
    const float* __restrict__ ws_in, float* __restrict__ mask) {
    const int b = blockIdx.x;
    const int t = threadIdx.x;                 // 0..255
    __shared__ float sm[WW * FF];              // 2048 floats
    const float* part = ws_in + WS_PARTIAL + (size_t)b * 4 * (WW * FF);

    float v[8];
#pragma unroll
    for (int j = 0; j < 8; ++j) {
        const int i = t + 256 * j;
        float s = part[i] + part[WW * FF + i] + part[2 * WW * FF + i] +
                  part[3 * WW * FF + i];
        v[j] = s * (1.f / HH);
        sm[i] = v[j];
    }
    __syncthreads();

    // tree max over w: sm[w*32+f] <- max(sm[w*32+f], sm[(w+s)*32+f])
    for (int s = WW / 2; s > 0; s >>= 1) {
#pragma unroll
        for (int j = 0; j < 8; ++j) {
            const int i = t + 256 * j;
            const int w = i >> 5;
            if (w < s) sm[i] = fmaxf(sm[i], sm[i + s * FF]);
        }
        __syncthreads();
    }
    // sm[0..31] now holds per-f max over w
#pragma unroll
    for (int j = 0; j < 8; ++j) {
        const int i = t + 256 * j;
        mask[(size_t)b * WW * FF + i] = v[j] / sm[i & (FF - 1)];
    }
}

// ---------------------------------------------------------------------------
// Kernel B: out[b,u,y,x,f] = mean_c(lfi[b,u,y,x,:]) * mask[b,y,f]
// grid = (1296, B). Per thread: f4 = base&7 is CONSTANT across the k-loop
// (k stride 256 ≡ 0 mod 8) and y_k = (y0 + k/2) & 63 with y0 wave-uniform
// -> 4 hoisted mask loads (L1 broadcast), 8 lfi loads at r0+32k, 8 coalesced
// NT fx4 stores (1KB/wave/instr).
// ---------------------------------------------------------------------------
#define NPT 8
__global__ __launch_bounds__(256) void out_kernel(
    const fx4* __restrict__ lfi4,   // [B*U*H*W] fx4 (C=4 contiguous)
    const fx4* __restrict__ mask4,  // [B*W*F/4] fx4
    fx4* __restrict__ out4) {       // [B*U*H*W*F/4]
    const int b = blockIdx.y;
    const fx4* __restrict__ lfiB  = lfi4  + (size_t)b * UU * HH * WW;
    const fx4* __restrict__ maskB = mask4 + (size_t)b * WW * (FF / 4);
    fx4* __restrict__ outB        = out4  + (size_t)b * UU * HH * WW * (FF / 4);

    const size_t base = (size_t)blockIdx.x * (256 * NPT) + threadIdx.x;
    const size_t r0 = base >> 3;               // lfi fx4 index for k=0
    const int f4 = (int)(base & 7);
    const int y0 = (int)((r0 >> 6) & 63);      // wave-uniform

    fx4 mk[NPT / 2];
#pragma unroll
    for (int j = 0; j < NPT / 2; ++j)
        mk[j] = maskB[((y0 + j) & 63) * 8 + f4];

    fx4 lf[NPT];
#pragma unroll
    for (int k = 0; k < NPT; ++k) lf[k] = lfiB[r0 + (size_t)k * 32];

#pragma unroll
    for (int k = 0; k < NPT; ++k) {
        const float m = (lf[k].x + lf[k].y + lf[k].z + lf[k].w) * 0.25f;
        fx4 o = m * mk[k >> 1];
        __builtin_nontemporal_store(o, &outB[base + (size_t)k * 256]);
    }
}

extern "C" void kernel_launch(void* const* d_in, const int* in_sizes, int n_in,
                              void* d_out, int out_size, void* d_ws, size_t ws_size,
                              hipStream_t stream) {
    const float* lfi = (const float*)d_in[0];
    const float* fmaps = (const float*)d_in[1];
    float* out = (float*)d_out;
    float* ws = (float*)d_ws;
    float* mask = ws + WS_MASK;

    mask_partial_kernel<<<dim3(4, BB), 1024, 0, stream>>>(fmaps, ws);
    mask_norm_kernel<<<BB, 256, 0, stream>>>(ws, mask);

    const size_t perB4 = (size_t)UU * HH * WW * (FF / 4);  // 2,654,208
    const int grid_x = (int)(perB4 / (256 * NPT));         // 1296 (exact)
    dim3 grid(grid_x, BB);
    out_kernel<<<grid, 256, 0, stream>>>(
        (const fx4*)lfi, (const fx4*)mask, (fx4*)out);
}

// Round 10
// 197.684 us; speedup vs baseline: 1.0785x; 1.0141x over previous
//
#include <hip/hip_runtime.h>
#include <hip/hip_bf16.h>

// Shapes (fixed by the reference):
// lfi:    [B, U, H, W, C] f32   B=4, U=81, H=64, W=64, C=4
// f_maps: [B, H, W, F]    f32   F=32
// out:    [B, U, H, W, F] f32
#define BB 4
#define UU 81
#define HH 64
#define WW 64
#define CC 4
#define FF 32

typedef float fx4 __attribute__((ext_vector_type(4)));

// ws layout (floats): [0, 32768)     = partial[b][hs][slot]  (4*4*2048)
//                     [32768, 40960) = mask[b][y][f]         (4*2048)
#define WS_PARTIAL 0
#define WS_MASK 32768

// ---------------------------------------------------------------------------
// Kernel A1: partial h-sums. grid = (4 h-slices, 4 b), 1024 threads.
// ---------------------------------------------------------------------------
__global__ __launch_bounds__(1024) void mask_partial_kernel(
    const float* __restrict__ fmaps, float* __restrict__ ws) {
    const int hs = blockIdx.x;                 // 0..3
    const int b = blockIdx.y;
    const int t = threadIdx.x;                 // 0..1023
    const float* fb = fmaps + (size_t)b * HH * WW * FF + (size_t)hs * 16 * WW * FF;
    float* part = ws + WS_PARTIAL + ((size_t)b * 4 + hs) * (WW * FF);

#pragma unroll
    for (int r = 0; r < 2; ++r) {
        const int idx = t + r * 1024;          // slot = w*F + f
        float s = 0.f;
#pragma unroll
        for (int h = 0; h < 16; ++h) s += fb[h * WW * FF + idx];
        part[idx] = s;
    }
}

// ---------------------------------------------------------------------------
// Kernel A2: hv = sum of 4 partials (L2-hot), tree-max over w per (b,f),
// write normalized mask. grid = 4 (b), 256 threads, 8 slots/thread.
// ---------------------------------------------------------------------------
__global__ __launch_bounds__(256) void mask_norm_kernel(
    const float* __restrict__ ws_in, float* __restrict__ mask) {
    const int b = blockIdx.x;
    const int t = threadIdx.x;                 // 0..255
    __shared__ float sm[WW * FF];              // 2048 floats
    const float* part = ws_in + WS_PARTIAL + (size_t)b * 4 * (WW * FF);

    float v[8];
#pragma unroll
    for (int j = 0; j < 8; ++j) {
        const int i = t + 256 * j;
        float s = part[i] + part[WW * FF + i] + part[2 * WW * FF + i] +
                  part[3 * WW * FF + i];
        v[j] = s * (1.f / HH);
        sm[i] = v[j];
    }
    __syncthreads();

    // tree max over w: sm[w*32+f] <- max(sm[w*32+f], sm[(w+s)*32+f])
    for (int s = WW / 2; s > 0; s >>= 1) {
#pragma unroll
        for (int j = 0; j < 8; ++j) {
            const int i = t + 256 * j;
            const int w = i >> 5;
            if (w < s) sm[i] = fmaxf(sm[i], sm[i + s * FF]);
        }
        __syncthreads();
    }
    // sm[0..31] now holds per-f max over w
#pragma unroll
    for (int j = 0; j < 8; ++j) {
        const int i = t + 256 * j;
        mask[(size_t)b * WW * FF + i] = v[j] / sm[i & (FF - 1)];
    }
}

// ---------------------------------------------------------------------------
// Kernel B: out[b,u,y,x,f] = mean_c(lfi[b,u,y,x,:]) * mask[b,y,f]
// Identical to round 9 EXCEPT: plain stores instead of nontemporal
// (single-variable A/B — NT bypasses L2 write-combining and is suspected
// of causing partial-burst HBM writes at ~1/3 the fill kernel's rate).
// ---------------------------------------------------------------------------
#define NPT 8
__global__ __launch_bounds__(256) void out_kernel(
    const fx4* __restrict__ lfi4,   // [B*U*H*W] fx4 (C=4 contiguous)
    const fx4* __restrict__ mask4,  // [B*W*F/4] fx4
    fx4* __restrict__ out4) {       // [B*U*H*W*F/4]
    const int b = blockIdx.y;
    const fx4* __restrict__ lfiB  = lfi4  + (size_t)b * UU * HH * WW;
    const fx4* __restrict__ maskB = mask4 + (size_t)b * WW * (FF / 4);
    fx4* __restrict__ outB        = out4  + (size_t)b * UU * HH * WW * (FF / 4);

    const size_t base = (size_t)blockIdx.x * (256 * NPT) + threadIdx.x;
    const size_t r0 = base >> 3;               // lfi fx4 index for k=0
    const int f4 = (int)(base & 7);
    const int y0 = (int)((r0 >> 6) & 63);      // wave-uniform

    fx4 mk[NPT / 2];
#pragma unroll
    for (int j = 0; j < NPT / 2; ++j)
        mk[j] = maskB[((y0 + j) & 63) * 8 + f4];

    fx4 lf[NPT];
#pragma unroll
    for (int k = 0; k < NPT; ++k) lf[k] = lfiB[r0 + (size_t)k * 32];

#pragma unroll
    for (int k = 0; k < NPT; ++k) {
        const float m = (lf[k].x + lf[k].y + lf[k].z + lf[k].w) * 0.25f;
        outB[base + (size_t)k * 256] = m * mk[k >> 1];
    }
}

extern "C" void kernel_launch(void* const* d_in, const int* in_sizes, int n_in,
                              void* d_out, int out_size, void* d_ws, size_t ws_size,
                              hipStream_t stream) {
    const float* lfi = (const float*)d_in[0];
    const float* fmaps = (const float*)d_in[1];
    float* out = (float*)d_out;
    float* ws = (float*)d_ws;
    float* mask = ws + WS_MASK;

    mask_partial_kernel<<<dim3(4, BB), 1024, 0, stream>>>(fmaps, ws);
    mask_norm_kernel<<<BB, 256, 0, stream>>>(ws, mask);

    const size_t perB4 = (size_t)UU * HH * WW * (FF / 4);  // 2,654,208
    const int grid_x = (int)(perB4 / (256 * NPT));         // 1296 (exact)
    dim3 grid(grid_x, BB);
    out_kernel<<<grid, 256, 0, stream>>>(
        (const fx4*)lfi, (const fx4*)mask, (fx4*)out);
}